// Round 9
// baseline (367.968 us; speedup 1.0000x reference)
//
#include <hip/hip_runtime.h>

#define NB 2048
#define TS 128
#define NS 16
#define MS 8
#define CS 4
#define DTC 0.01f

// ws layout (floats) — ~620 KB total
#define K_OFF 0
#define K_SZ (TS*NS*MS)           // 16,384
#define G_OFF (K_OFF + K_SZ)
#define G_SZ ((TS-1)*NS*NS)       // 32,512
#define PP_OFF (G_OFF + G_SZ)
#define PP_SZ (TS*NS*NS)          // 32,768
#define PF_OFF (PP_OFF + PP_SZ)
#define PF_SZ (TS*NS*NS)          // 32,768
#define A_OFF (PF_OFF + PF_SZ)
#define A_SZ (TS*NS*NS)           // 32,768 : A_t = (I-K H)F
#define M_OFF (A_OFF + A_SZ)
#define M_SZ (TS*NS*CS)           // 8,192  : M_t = DT(Bc - K HBc)

// explicit full-width shuffle within a 16-lane group (groups never span waves)
#define GSHFL(v, k) __shfl((v), ((tid & 48) | (k)), 64)

// ---------------------------------------------------------------------------
// Kernel A: batch-independent covariance recursion. 4 barrier-stages/step:
//   S1: TP = F*Pf (all)              ||  W = HF*Pf (tid<128)
//   S2: Pp = TP*F^T+Q (all, own)     ||  PHt = TP*(HF)^T+QHt (tid<128)
//                                    ||  S = W*(HF)^T+Rbar (tid 128..191)
//   S3: K-solve via per-thread register LU (tid<128)  ||  HP = H*Pp (tid>=128)
//   S4: Pf = Pp-K*HP; A_t = F-K*HF; M_t = DT(Bc-K*HBc); writes
// Identity: S = H Pp H^T + R = (HF) Pf (HF)^T + H Q H^T + R.
// No shuffles in this kernel.
// ---------------------------------------------------------------------------
__global__ __launch_bounds__(256) void cov_kernel(
    const float* __restrict__ Ag, const float* __restrict__ Hg,
    const float* __restrict__ Qg, const float* __restrict__ Rg,
    const float* __restrict__ P0g, const float* __restrict__ Bcg,
    float* __restrict__ Kw, float* __restrict__ Ppw, float* __restrict__ Pfw,
    float* __restrict__ Aw, float* __restrict__ Mw)
{
    __shared__ float Fs[NS][NS], Qs[NS][NS];
    __shared__ float Hs[MS][NS], HFs[MS][NS], QHt[NS][MS];
    __shared__ float Rs[MS][MS], Rbar[MS][MS], HBcs[MS][CS], Bcs[NS][CS];
    __shared__ float Pf[NS][NS], Pp[NS][NS], TP[NS][NS], Ws[MS][NS];
    __shared__ float PHt[NS][MS], HP[MS][NS], Ks[NS][MS];
    __shared__ float Sg[MS][MS];

    const int tid = threadIdx.x;
    const int i = tid >> 4, j = tid & 15;

    float Fri[NS];
#pragma unroll
    for (int k = 0; k < NS; ++k) Fri[k] = ((i == k) ? 1.f : 0.f) + DTC * Ag[i*NS + k];

    Fs[i][j] = ((i == j) ? 1.f : 0.f) + DTC * Ag[tid];
    Qs[i][j] = Qg[tid];
    if (tid < MS*NS) Hs[tid >> 4][tid & 15] = Hg[tid];
    if (tid < MS*MS) Rs[tid >> 3][tid & 7] = Rg[tid];
    if (tid < NS*CS) Bcs[tid >> 2][tid & 3] = Bcg[tid];
    Pf[i][j] = P0g[tid];                 // P0 identical for all batches
    __syncthreads();

    // one-time: HF = H*F (8x16), QHt = Q*H^T (16x8), HBc = H*Bc (8x4)
    if (tid < MS*NS) {
        const int a = tid >> 4, k = tid & 15;
        float acc = 0.f;
#pragma unroll
        for (int m = 0; m < NS; ++m) acc += Hs[a][m] * Fs[m][k];
        HFs[a][k] = acc;
    } else {
        const int e = tid - 128, ii = e >> 3, b = e & 7;
        float acc = 0.f;
#pragma unroll
        for (int k = 0; k < NS; ++k) acc += Qs[ii][k] * Hs[b][k];
        QHt[ii][b] = acc;
    }
    if (tid < MS*CS) {
        const int r = tid >> 2, c = tid & 3;
        float acc = 0.f;
#pragma unroll
        for (int k = 0; k < NS; ++k) acc += Hs[r][k] * Bcs[k][c];
        HBcs[r][c] = acc;
    }
    __syncthreads();

    // one-time: Rbar = H*QHt + R (8x8)
    if (tid < MS*MS) {
        const int r = tid >> 3, c = tid & 7;
        float acc = Rs[r][c];
#pragma unroll
        for (int k = 0; k < NS; ++k) acc += Hs[r][k] * QHt[k][c];
        Rbar[r][c] = acc;
    }
    __syncthreads();

    for (int t = 0; t < TS; ++t) {
        // ---- S1: TP = F*Pf (all 256)  ||  W = HF*Pf (tid<128) ----
        {
            float a0 = 0.f, a1 = 0.f;
#pragma unroll
            for (int k = 0; k < NS; k += 2) { a0 += Fri[k]*Pf[k][j]; a1 += Fri[k+1]*Pf[k+1][j]; }
            TP[i][j] = a0 + a1;
            if (tid < MS*NS) {
                const int a = tid >> 4, jj = tid & 15;
                float w0 = 0.f, w1 = 0.f;
#pragma unroll
                for (int k = 0; k < NS; k += 2) { w0 += HFs[a][k]*Pf[k][jj]; w1 += HFs[a][k+1]*Pf[k+1][jj]; }
                Ws[a][jj] = w0 + w1;
            }
        }
        __syncthreads();

        // ---- S2: Pp (all, own entry) || PHt (tid<128) || S (tid 128..191) ----
        {
            float c0 = Qs[i][j], c1 = 0.f;
#pragma unroll
            for (int k = 0; k < NS; k += 2) { c0 += TP[i][k]*Fs[j][k]; c1 += TP[i][k+1]*Fs[j][k+1]; }
            const float ppv = c0 + c1;
            Pp[i][j] = ppv;
            Ppw[t*(NS*NS) + tid] = ppv;
            if (tid < NS*MS) {
                const int ii = tid >> 3, l = tid & 7;
                float b0 = QHt[ii][l], b1 = 0.f;
#pragma unroll
                for (int k = 0; k < NS; k += 2) { b0 += TP[ii][k]*HFs[l][k]; b1 += TP[ii][k+1]*HFs[l][k+1]; }
                PHt[ii][l] = b0 + b1;
            } else if (tid < 192) {
                const int e = tid - 128, r = e >> 3, c = e & 7;
                float s0 = Rbar[r][c], s1 = 0.f;
#pragma unroll
                for (int k = 0; k < NS; k += 2) { s0 += Ws[r][k]*HFs[c][k]; s1 += Ws[r][k+1]*HFs[c][k+1]; }
                Sg[r][c] = s0 + s1;
            }
        }
        __syncthreads();

        // ---- S3: K-solve (tid<128, register LU)  ||  HP = H*Pp (tid>=128) ----
        if (tid < 128) {
            const int ii = tid >> 3, m = tid & 7;
            float Sr[MS][MS];
#pragma unroll
            for (int a = 0; a < MS; ++a) {
                const float4 x0 = *(const float4*)&Sg[a][0];
                const float4 x1 = *(const float4*)&Sg[a][4];
                Sr[a][0]=x0.x; Sr[a][1]=x0.y; Sr[a][2]=x0.z; Sr[a][3]=x0.w;
                Sr[a][4]=x1.x; Sr[a][5]=x1.y; Sr[a][6]=x1.z; Sr[a][7]=x1.w;
            }
            float rds[MS];
#pragma unroll
            for (int p = 0; p < MS; ++p) {
                const float rd = 1.f / Sr[p][p]; rds[p] = rd;
#pragma unroll
                for (int r = p+1; r < MS; ++r) {
                    const float f = Sr[r][p] * rd; Sr[r][p] = f;
#pragma unroll
                    for (int c = p+1; c < MS; ++c) Sr[r][c] -= f * Sr[p][c];
                }
            }
            float yv[MS];
#pragma unroll
            for (int r = 0; r < MS; ++r) {
                float v = (r == m) ? 1.f : 0.f;
#pragma unroll
                for (int c = 0; c < r; ++c) v -= Sr[r][c] * yv[c];
                yv[r] = v;
            }
            float xv[MS];
#pragma unroll
            for (int r = MS-1; r >= 0; --r) {
                float v = yv[r];
#pragma unroll
                for (int c = r+1; c < MS; ++c) v -= Sr[r][c] * xv[c];
                xv[r] = v * rds[r];
            }
            const float4 p0 = *(const float4*)&PHt[ii][0];
            const float4 p1 = *(const float4*)&PHt[ii][4];
            float kv = p0.x*xv[0] + p0.y*xv[1] + p0.z*xv[2] + p0.w*xv[3]
                     + p1.x*xv[4] + p1.y*xv[5] + p1.z*xv[6] + p1.w*xv[7];
            Ks[ii][m] = kv;
            Kw[t*(NS*MS) + tid] = kv;
        } else {
            const int e = tid - 128, m = e >> 4, jj = e & 15;
            float v = 0.f;
#pragma unroll
            for (int k = 0; k < NS; ++k) v += Hs[m][k] * Pp[k][jj];
            HP[m][jj] = v;
        }
        __syncthreads();

        // ---- S4: Pf = Pp - K*HP ; A_t = F - K*HF ; M_t = DT(Bc - K*HBc) ----
        {
            float kr[MS];
            *(float4*)&kr[0] = *(const float4*)&Ks[i][0];
            *(float4*)&kr[4] = *(const float4*)&Ks[i][4];
            float pf = Pp[i][j], av = Fs[i][j];
#pragma unroll
            for (int m = 0; m < MS; ++m) { pf -= kr[m] * HP[m][j]; av -= kr[m] * HFs[m][j]; }
            Pf[i][j] = pf;
            Pfw[t*(NS*NS) + tid] = pf;
            Aw[t*(NS*NS) + tid] = av;
            if (tid < NS*CS) {
                const int ri = tid >> 2, c = tid & 3;
                float mv = Bcs[ri][c];
#pragma unroll
                for (int m = 0; m < MS; ++m) mv -= Ks[ri][m] * HBcs[m][c];
                Mw[t*(NS*CS) + tid] = DTC * mv;
            }
        }
        __syncthreads();
    }
}

// ---------------------------------------------------------------------------
// Kernel B: smoother gains, parallel over t (unchanged, passing).
// ---------------------------------------------------------------------------
__global__ __launch_bounds__(256) void g_kernel(
    const float* __restrict__ Ag,
    const float* __restrict__ Ppw, const float* __restrict__ Pfw,
    float* __restrict__ Gw)
{
    const int t   = blockIdx.x;        // 0..TS-2
    const int tid = threadIdx.x;
    const int r = tid >> 4, cl = tid & 15;

    __shared__ float aug0[NS][NS], aug1[NS][NS], Pfs[NS][NS], Ws[NS][NS];

    float Frc[NS];
#pragma unroll
    for (int k = 0; k < NS; ++k) Frc[k] = ((cl == k) ? 1.f : 0.f) + DTC * Ag[cl*NS + k];

    aug0[r][cl] = Ppw[(t+1)*(NS*NS) + tid];
    aug1[r][cl] = (r == cl) ? 1.f : 0.f;
    Pfs[r][cl]  = Pfw[t*(NS*NS) + tid];
    __syncthreads();

    for (int p = 0; p < NS; ++p) {
        const float a0 = aug0[r][cl], a1 = aug1[r][cl];
        const float d  = aug0[p][p];
        const float pa = aug0[p][cl], pb = aug1[p][cl];
        const float f  = aug0[r][p];
        __syncthreads();
        const float rd = 1.f / d;
        if (r == p) { aug0[r][cl] = pa * rd;       aug1[r][cl] = pb * rd; }
        else        { const float frd = f * rd;
                      aug0[r][cl] = a0 - frd * pa; aug1[r][cl] = a1 - frd * pb; }
        __syncthreads();
    }

    float w0 = 0.f, w1 = 0.f;
#pragma unroll
    for (int k = 0; k < NS; k += 2) { w0 += Pfs[r][k]*Frc[k]; w1 += Pfs[r][k+1]*Frc[k+1]; }
    Ws[r][cl] = w0 + w1;
    __syncthreads();

    float g0 = 0.f, g1 = 0.f;
#pragma unroll
    for (int k = 0; k < NS; k += 2) { g0 += Ws[r][k]*aug1[k][cl]; g1 += Ws[r][k+1]*aug1[k+1][cl]; }
    Gw[t*(NS*NS) + tid] = g0 + g1;
}

// ---------------------------------------------------------------------------
// Kernel P: b_t = M_t*u_t + K_t*y_t, written into d_out[b][t][:]. (unchanged)
// ---------------------------------------------------------------------------
__global__ __launch_bounds__(256) void prep_kernel(
    const float* __restrict__ ctrl, const float* __restrict__ obsg,
    const float* __restrict__ Kw, const float* __restrict__ Mw,
    float* __restrict__ outp)
{
    const int g = blockIdx.x * 256 + threadIdx.x;      // 0 .. NB*TS*NS-1
    const int b = g >> 11;
    const int rem = g & 2047;
    const int t = rem >> 4, i = rem & 15;

    const float4 u  = *(const float4*)(ctrl + (size_t)b*TS*CS + t*CS);
    const float4 y0 = *(const float4*)(obsg + (size_t)b*TS*MS + t*MS);
    const float4 y1 = *(const float4*)(obsg + (size_t)b*TS*MS + t*MS + 4);
    const float4 mr = *(const float4*)(Mw + t*(NS*CS) + i*CS);
    const float4 k0 = *(const float4*)(Kw + t*(NS*MS) + i*MS);
    const float4 k1 = *(const float4*)(Kw + t*(NS*MS) + i*MS + 4);

    float v = mr.x*u.x + mr.y*u.y + mr.z*u.z + mr.w*u.w;
    v += k0.x*y0.x + k0.y*y0.y + k0.z*y0.z + k0.w*y0.w;
    v += k1.x*y1.x + k1.y*y1.y + k1.z*y1.z + k1.w*y1.w;
    outp[g] = v;
}

// ---------------------------------------------------------------------------
// Kernel C: forward filter, s = A_t*s + b_t. b_{t+1} is loaded BEFORE the
// store to ob[t] so the same-buffer load never waits on the store (alias
// stall was the round-8 suspect).
// ---------------------------------------------------------------------------
__global__ __launch_bounds__(256) void fwd_kernel(
    const float* __restrict__ s0g, const float* __restrict__ Aw,
    float* __restrict__ outp)
{
    const int tid  = threadIdx.x;
    const int lane = tid & 15;
    const int b    = blockIdx.x * 16 + (tid >> 4);

    float s = s0g[b*NS + lane];
    float* ob = outp + (size_t)b * TS * NS;

    float4 a0 = *(const float4*)(Aw + lane*NS);
    float4 a1 = *(const float4*)(Aw + lane*NS + 4);
    float4 a2 = *(const float4*)(Aw + lane*NS + 8);
    float4 a3 = *(const float4*)(Aw + lane*NS + 12);
    float bt = ob[lane];   // b_0

    for (int t = 0; t < TS; ++t) {
        float4 n0, n1, n2, n3;
        float btn;
        if (t + 1 < TS) {
            const float* ap = Aw + (t+1)*(NS*NS) + lane*NS;
            n0 = *(const float4*)(ap);     n1 = *(const float4*)(ap + 4);
            n2 = *(const float4*)(ap + 8); n3 = *(const float4*)(ap + 12);
            btn = ob[(t+1)*NS + lane];     // load BEFORE the ob[t] store
        }
        float p0 = bt, p1 = 0.f, p2 = 0.f, p3 = 0.f;
        p0 += a0.x*GSHFL(s,0)  + a0.y*GSHFL(s,1);
        p1 += a0.z*GSHFL(s,2)  + a0.w*GSHFL(s,3);
        p2 += a1.x*GSHFL(s,4)  + a1.y*GSHFL(s,5);
        p3 += a1.z*GSHFL(s,6)  + a1.w*GSHFL(s,7);
        p0 += a2.x*GSHFL(s,8)  + a2.y*GSHFL(s,9);
        p1 += a2.z*GSHFL(s,10) + a2.w*GSHFL(s,11);
        p2 += a3.x*GSHFL(s,12) + a3.y*GSHFL(s,13);
        p3 += a3.z*GSHFL(s,14) + a3.w*GSHFL(s,15);
        const float sn = (p0 + p1) + (p2 + p3);
        ob[t*NS + lane] = sn;
        s = sn;
        if (t + 1 < TS) { a0 = n0; a1 = n1; a2 = n2; a3 = n3; bt = btn; }
    }
}

// ---------------------------------------------------------------------------
// Kernel D: backward RTS smoother, in place on d_out. sf_{t-1} prefetched
// BEFORE the ob[t] store (same alias-stall fix).
// ---------------------------------------------------------------------------
__global__ __launch_bounds__(256) void bwd_kernel(
    const float* __restrict__ Gw, const float* __restrict__ ctrl,
    const float* __restrict__ Ag, const float* __restrict__ Bcg,
    float* __restrict__ outp)
{
    const int tid  = threadIdx.x;
    const int lane = tid & 15;
    const int b    = blockIdx.x * 16 + (tid >> 4);

    float Fi[NS], Bci[CS];
#pragma unroll
    for (int k = 0; k < NS; ++k) Fi[k] = ((lane == k) ? 1.f : 0.f) + DTC * Ag[lane*NS + k];
#pragma unroll
    for (int k = 0; k < CS; ++k) Bci[k] = DTC * Bcg[lane*CS + k];

    const float* up = ctrl + (size_t)b * TS * CS;
    float* ob = outp + (size_t)b * TS * NS;

    float ss = ob[(TS-1)*NS + lane];
    float sf = ob[(TS-2)*NS + lane];

    for (int t = TS-2; t >= 0; --t) {
        float sfn;
        if (t > 0) sfn = ob[(t-1)*NS + lane];   // prefetch BEFORE the store

        const float4 u = *(const float4*)(up + (t+1)*CS);
        float p0 = Bci[0]*u.x + Bci[1]*u.y, p1 = Bci[2]*u.z + Bci[3]*u.w, p2 = 0.f, p3 = 0.f;
#pragma unroll
        for (int k = 0; k < NS; k += 4) {
            p0 += Fi[k  ] * GSHFL(sf, k);
            p1 += Fi[k+1] * GSHFL(sf, k+1);
            p2 += Fi[k+2] * GSHFL(sf, k+2);
            p3 += Fi[k+3] * GSHFL(sf, k+3);
        }
        const float diff = ss - ((p0 + p1) + (p2 + p3));

        const float4 g0 = *(const float4*)(Gw + t*(NS*NS) + lane*NS);
        const float4 g1 = *(const float4*)(Gw + t*(NS*NS) + lane*NS + 4);
        const float4 g2 = *(const float4*)(Gw + t*(NS*NS) + lane*NS + 8);
        const float4 g3 = *(const float4*)(Gw + t*(NS*NS) + lane*NS + 12);

        float a0 = g0.x*GSHFL(diff,0)  + g0.y*GSHFL(diff,1);
        a0      += g0.z*GSHFL(diff,2)  + g0.w*GSHFL(diff,3);
        float a1 = g1.x*GSHFL(diff,4)  + g1.y*GSHFL(diff,5);
        a1      += g1.z*GSHFL(diff,6)  + g1.w*GSHFL(diff,7);
        float a2 = g2.x*GSHFL(diff,8)  + g2.y*GSHFL(diff,9);
        a2      += g2.z*GSHFL(diff,10) + g2.w*GSHFL(diff,11);
        float a3 = g3.x*GSHFL(diff,12) + g3.y*GSHFL(diff,13);
        a3      += g3.z*GSHFL(diff,14) + g3.w*GSHFL(diff,15);

        const float sn = sf + ((a0 + a1) + (a2 + a3));
        ob[t*NS + lane] = sn;
        ss = sn;
        sf = sfn;
    }
}

extern "C" void kernel_launch(void* const* d_in, const int* in_sizes, int n_in,
                              void* d_out, int out_size, void* d_ws, size_t ws_size,
                              hipStream_t stream)
{
    (void)out_size; (void)ws_size;

    // Self-resolving input mapping from element counts (the round-4 fix):
    const float *s0 = nullptr, *P0 = nullptr, *ctrl = nullptr, *obs = nullptr;
    const float *A = nullptr, *Bc = nullptr, *H = nullptr, *Q = nullptr, *R = nullptr;
    for (int idx = 0; idx < n_in; ++idx) {
        const float* p = (const float*)d_in[idx];
        switch (in_sizes[idx]) {
            case NB*NS:        s0   = p; break;           // 32768
            case NB*NS*NS:     P0   = p; break;           // 524288
            case NB*TS*CS:     ctrl = p; break;           // 1048576
            case NB*TS*MS:     obs  = p; break;           // 2097152
            case MS*NS:        H    = p; break;           // 128
            case NS*NS:        if (!A)  A  = p; else Q = p; break;   // 256
            case MS*MS:        if (!Bc) Bc = p; else R = p; break;   // 64
            default: break;
        }
    }

    float* ws  = (float*)d_ws;
    float* Kw  = ws + K_OFF;
    float* Gw  = ws + G_OFF;
    float* Ppw = ws + PP_OFF;
    float* Pfw = ws + PF_OFF;
    float* Aw  = ws + A_OFF;
    float* Mw  = ws + M_OFF;
    float* out = (float*)d_out;

    hipLaunchKernelGGL(cov_kernel,  dim3(1),            dim3(256), 0, stream,
                       A, H, Q, R, P0, Bc, Kw, Ppw, Pfw, Aw, Mw);
    hipLaunchKernelGGL(g_kernel,    dim3(TS-1),         dim3(256), 0, stream, A, Ppw, Pfw, Gw);
    hipLaunchKernelGGL(prep_kernel, dim3(NB*TS*NS/256), dim3(256), 0, stream, ctrl, obs, Kw, Mw, out);
    hipLaunchKernelGGL(fwd_kernel,  dim3(NB/16),        dim3(256), 0, stream, s0, Aw, out);
    hipLaunchKernelGGL(bwd_kernel,  dim3(NB/16),        dim3(256), 0, stream, Gw, ctrl, A, Bc, out);
}